// Round 10
// baseline (764.165 us; speedup 1.0000x reference)
//
#include <hip/hip_runtime.h>
#include <hip/hip_cooperative_groups.h>
#include <math.h>

namespace cg = cooperative_groups;

#define NROWS 8192
#define NFEATD 500
#define NHID 128
#define NCLS 40
#define CAP 64             // max nnz/row (mean ~16.4, binomial max ~41)
#define FCIN_UNITS (NROWS / 8)    // 1024 (8 rows each)
#define CSR_UNITS  (NROWS / 4)    // 2048 (4 rows each)
#define LAYER_UNITS (NROWS / 8)   // 1024 (8 rows each)
#define SMEM_FLOATS 4032          // max(8*504 fcin, 2*8*128 layer)

typedef float f32x4 __attribute__((ext_vector_type(4)));

// ===========================================================================
// Device bodies (shared by cooperative mega-kernel and multi-kernel fallback)
// ===========================================================================

// fcin unit: 8 rows. h = 0.9*relu(x@fc_in_w + b) + 0.1*c ; h0 = h  (R4-verbatim)
__device__ __forceinline__ void d_fcin(
    const float* __restrict__ x, const float* __restrict__ w,
    const float* __restrict__ b, const float* __restrict__ cvec,
    float* __restrict__ h, float* __restrict__ h0,
    int r0, int tid, float* smemf)
{
    float (*xs)[504] = (float(*)[504])smemf;
    __syncthreads();                       // protect LDS reuse across units
    for (int rr = 0; rr < 8; ++rr)
        for (int k = tid; k < NFEATD; k += 256)
            xs[rr][k] = x[(size_t)(r0 + rr) * NFEATD + k];
    __syncthreads();
    int col = tid & 127;
    int rg = tid >> 7;
    float bias = b[col];
    float acc[4] = {bias, bias, bias, bias};
    for (int k4 = 0; k4 < NFEATD / 4; ++k4) {
        int k = k4 * 4;
        f32x4 a0 = *(const f32x4*)&xs[rg * 4 + 0][k];
        f32x4 a1 = *(const f32x4*)&xs[rg * 4 + 1][k];
        f32x4 a2 = *(const f32x4*)&xs[rg * 4 + 2][k];
        f32x4 a3 = *(const f32x4*)&xs[rg * 4 + 3][k];
        float w0 = w[(k + 0) * NHID + col];
        float w1 = w[(k + 1) * NHID + col];
        float w2 = w[(k + 2) * NHID + col];
        float w3 = w[(k + 3) * NHID + col];
        acc[0] += a0.x * w0 + a0.y * w1 + a0.z * w2 + a0.w * w3;
        acc[1] += a1.x * w0 + a1.y * w1 + a1.z * w2 + a1.w * w3;
        acc[2] += a2.x * w0 + a2.y * w1 + a2.z * w2 + a2.w * w3;
        acc[3] += a3.x * w0 + a3.y * w1 + a3.z * w2 + a3.w * w3;
    }
    float cv = cvec[col];
#pragma unroll
    for (int rr = 0; rr < 4; ++rr) {
        float hv = 0.9f * fmaxf(acc[rr], 0.0f) + 0.1f * cv;
        size_t o = (size_t)(r0 + rg * 4 + rr) * NHID + col;
        h[o] = hv;
        h0[o] = hv;
    }
}

// csr unit: 4 rows (one per wave). Ordered CSR + dinv = rsqrt(deg+1). (R4-verbatim)
__device__ __forceinline__ void d_csr(
    const float* __restrict__ adj, float* __restrict__ dinv,
    int* __restrict__ cnts, int* __restrict__ cols, int rbase, int tid)
{
    int r = rbase + (tid >> 6);
    int lane = tid & 63;
    const f32x4* row4 = (const f32x4*)(adj + (size_t)r * NROWS);
    int* mycols = cols + (size_t)r * CAP;
    unsigned long long lt = (1ull << lane) - 1ull;
    int cnt = 0;
    for (int it = 0; it < NROWS / 256; ++it) {
        f32x4 v = __builtin_nontemporal_load(&row4[it * 64 + lane]);
        int base = it * 256 + 4 * lane;
        bool nz; unsigned long long m;
        nz = (v.x != 0.0f); m = __ballot(nz);
        if (nz) { int p = cnt + __popcll(m & lt); mycols[p < CAP ? p : CAP - 1] = base; }
        cnt += __popcll(m);
        nz = (v.y != 0.0f); m = __ballot(nz);
        if (nz) { int p = cnt + __popcll(m & lt); mycols[p < CAP ? p : CAP - 1] = base + 1; }
        cnt += __popcll(m);
        nz = (v.z != 0.0f); m = __ballot(nz);
        if (nz) { int p = cnt + __popcll(m & lt); mycols[p < CAP ? p : CAP - 1] = base + 2; }
        cnt += __popcll(m);
        nz = (v.w != 0.0f); m = __ballot(nz);
        if (nz) { int p = cnt + __popcll(m & lt); mycols[p < CAP ? p : CAP - 1] = base + 3; }
        cnt += __popcll(m);
    }
    if (lane == 0) {
        cnts[r] = cnt < CAP ? cnt : CAP;
        dinv[r] = rsqrtf((float)cnt + 1.0f);
    }
}

// layer unit: 8 rows. gather -> LDS, fused dual GEMM (4x1 tile), epilogue.
// edge_dinv: gather multiplies per-edge dinv (input is h); else input is ht=dinv*h.
// final_layer: apply fcout from LDS; else write htout = dinv*h_out.
__device__ __forceinline__ void d_layer(
    const float* __restrict__ hin, const float* __restrict__ h0,
    const float* __restrict__ dinv, const int* __restrict__ cnts,
    const int* __restrict__ cols,
    const float* __restrict__ wlin, const float* __restrict__ blin,
    const float* __restrict__ wgm, const float* __restrict__ bg,
    float beta, float* __restrict__ htout,
    const float* __restrict__ fow, const float* __restrict__ fob,
    float* __restrict__ out, int edge_dinv, int final_layer,
    int r0, int tid, float* smemf)
{
    float (*ahs)[NHID] = (float(*)[NHID])smemf;
    float (*ss)[NHID]  = (float(*)[NHID])(smemf + 8 * NHID);
    int lane = tid & 63;
    int wid = tid >> 6;
    const float2* h2 = (const float2*)hin;
    const float2* h02 = (const float2*)h0;

    __syncthreads();                       // protect LDS reuse across units
    for (int rr = 2 * wid; rr < 2 * wid + 2; ++rr) {
        int r = r0 + rr;
        int n = cnts[r];
        const int* mc = cols + (size_t)r * CAP;
        float ax = 0.f, ay = 0.f;
        int e = 0;
        if (edge_dinv) {
            for (; e + 4 <= n; e += 4) {
                int j0 = mc[e], j1 = mc[e + 1], j2 = mc[e + 2], j3 = mc[e + 3];
                float d0 = dinv[j0], d1 = dinv[j1], d2 = dinv[j2], d3 = dinv[j3];
                float2 v0 = h2[(size_t)j0 * 64 + lane];
                float2 v1 = h2[(size_t)j1 * 64 + lane];
                float2 v2 = h2[(size_t)j2 * 64 + lane];
                float2 v3 = h2[(size_t)j3 * 64 + lane];
                ax += d0 * v0.x + d1 * v1.x + d2 * v2.x + d3 * v3.x;
                ay += d0 * v0.y + d1 * v1.y + d2 * v2.y + d3 * v3.y;
            }
            for (; e < n; ++e) {
                int j = mc[e];
                float dj = dinv[j];
                float2 v = h2[(size_t)j * 64 + lane];
                ax += dj * v.x;
                ay += dj * v.y;
            }
            float di = dinv[r];
            float2 vi = h2[(size_t)r * 64 + lane];
            ax = di * (ax + di * vi.x);
            ay = di * (ay + di * vi.y);
        } else {
            for (; e + 4 <= n; e += 4) {
                int j0 = mc[e], j1 = mc[e + 1], j2 = mc[e + 2], j3 = mc[e + 3];
                float2 v0 = h2[(size_t)j0 * 64 + lane];
                float2 v1 = h2[(size_t)j1 * 64 + lane];
                float2 v2 = h2[(size_t)j2 * 64 + lane];
                float2 v3 = h2[(size_t)j3 * 64 + lane];
                ax += v0.x + v1.x + v2.x + v3.x;
                ay += v0.y + v1.y + v2.y + v3.y;
            }
            for (; e < n; ++e) {
                int j = mc[e];
                float2 v = h2[(size_t)j * 64 + lane];
                ax += v.x;
                ay += v.y;
            }
            float di = dinv[r];
            float2 ti = h2[(size_t)r * 64 + lane];
            ax = di * (ax + ti.x);
            ay = di * (ay + ti.y);
        }
        float2 h0v = h02[(size_t)r * 64 + lane];
        ((float2*)&ahs[rr][0])[lane] = make_float2(ax, ay);
        ((float2*)&ss[rr][0])[lane] =
            make_float2(0.9f * ax + 0.1f * h0v.x, 0.9f * ay + 0.1f * h0v.y);
    }
    __syncthreads();

    // GEMM: thread = 4 rows x 1 col (proven-fastest tile)
    int col = tid & 127;
    int rg = tid >> 7;
    float accl[4] = {0, 0, 0, 0};
    float accg[4] = {0, 0, 0, 0};
    for (int k4 = 0; k4 < NHID / 4; ++k4) {
        int k = 4 * k4;
        f32x4 a0 = *(const f32x4*)&ahs[rg * 4 + 0][k];
        f32x4 a1 = *(const f32x4*)&ahs[rg * 4 + 1][k];
        f32x4 a2 = *(const f32x4*)&ahs[rg * 4 + 2][k];
        f32x4 a3 = *(const f32x4*)&ahs[rg * 4 + 3][k];
        f32x4 s0 = *(const f32x4*)&ss[rg * 4 + 0][k];
        f32x4 s1 = *(const f32x4*)&ss[rg * 4 + 1][k];
        f32x4 s2 = *(const f32x4*)&ss[rg * 4 + 2][k];
        f32x4 s3 = *(const f32x4*)&ss[rg * 4 + 3][k];
        float wl0 = wlin[(k + 0) * NHID + col];
        float wl1 = wlin[(k + 1) * NHID + col];
        float wl2 = wlin[(k + 2) * NHID + col];
        float wl3 = wlin[(k + 3) * NHID + col];
        float wg0 = wgm[(k + 0) * NHID + col];
        float wg1 = wgm[(k + 1) * NHID + col];
        float wg2 = wgm[(k + 2) * NHID + col];
        float wg3 = wgm[(k + 3) * NHID + col];
        accl[0] += a0.x * wl0 + a0.y * wl1 + a0.z * wl2 + a0.w * wl3;
        accl[1] += a1.x * wl0 + a1.y * wl1 + a1.z * wl2 + a1.w * wl3;
        accl[2] += a2.x * wl0 + a2.y * wl1 + a2.z * wl2 + a2.w * wl3;
        accl[3] += a3.x * wl0 + a3.y * wl1 + a3.z * wl2 + a3.w * wl3;
        accg[0] += s0.x * wg0 + s0.y * wg1 + s0.z * wg2 + s0.w * wg3;
        accg[1] += s1.x * wg0 + s1.y * wg1 + s1.z * wg2 + s1.w * wg3;
        accg[2] += s2.x * wg0 + s2.y * wg1 + s2.z * wg2 + s2.w * wg3;
        accg[3] += s3.x * wg0 + s3.y * wg1 + s3.z * wg2 + s3.w * wg3;
    }
    float blv = blin[col], bgv = bg[col];
    float omb = 1.0f - beta;
    float o[4];
#pragma unroll
    for (int rr = 0; rr < 4; ++rr) {
        float sv = ss[rg * 4 + rr][col];
        float g = fmaxf(omb * sv + beta * accg[rr] + bgv, 0.0f);
        o[rr] = accl[rr] + blv + g;
    }

    if (!final_layer) {
#pragma unroll
        for (int rr = 0; rr < 4; ++rr) {
            int row = r0 + rg * 4 + rr;
            htout[(size_t)row * NHID + col] = dinv[row] * o[rr];
        }
    } else {
        __syncthreads();
#pragma unroll
        for (int rr = 0; rr < 4; ++rr)
            ahs[rg * 4 + rr][col] = o[rr];
        __syncthreads();
        int rr2 = tid >> 6, c2 = tid & 63;
        if (c2 < NCLS) {
#pragma unroll
            for (int half = 0; half < 2; ++half) {
                int lr = half * 4 + rr2;
                float acc = fob[c2];
                for (int k = 0; k < NHID; ++k)
                    acc += ahs[lr][k] * fow[k * NCLS + c2];
                out[(size_t)(r0 + lr) * NCLS + c2] = acc;
            }
        }
    }
}

// ===========================================================================
// Cooperative mega-kernel: persistent grid-stride over units, grid.sync
// between phases. Grid is sized by the host to the queried occupancy.
// ===========================================================================
__global__ __launch_bounds__(256, 4) void k_mega(
    const float* x, const float* adj,
    const float* fiw, const float* fib, const float* cvec,
    const float* wg_all, const float* bg_all,
    const float* wl_all, const float* bl_all,
    const float* fow, const float* fob,
    float* out, float* dinv, int* cnts, int* cols,
    float* hA, float* h0, float* htA, float* htB)
{
    cg::grid_group grid = cg::this_grid();
    __shared__ float smem[SMEM_FLOATS];
    const int tid = threadIdx.x;
    const int bid = blockIdx.x;
    const int G = gridDim.x;

    // ---- Phase A: fcin + CSR (parity order so HBM and VALU halves overlap)
    if (bid & 1) {
        for (int u = FCIN_UNITS + bid; u < FCIN_UNITS + CSR_UNITS; u += G)
            d_csr(adj, dinv, cnts, cols, (u - FCIN_UNITS) * 4, tid);
        for (int u = bid; u < FCIN_UNITS; u += G)
            d_fcin(x, fiw, fib, cvec, hA, h0, u * 8, tid, smem);
    } else {
        for (int u = bid; u < FCIN_UNITS; u += G)
            d_fcin(x, fiw, fib, cvec, hA, h0, u * 8, tid, smem);
        for (int u = FCIN_UNITS + bid; u < FCIN_UNITS + CSR_UNITS; u += G)
            d_csr(adj, dinv, cnts, cols, (u - FCIN_UNITS) * 4, tid);
    }
    __threadfence();
    grid.sync();

    // ---- Layers ----
    const float* hbufs[5]  = {hA, htA, htB, htA, nullptr};
    float* obufs[4]        = {htA, htB, htA, nullptr};
    for (int i = 0; i < 4; ++i) {
        float beta = logf(0.5f / (float)(i + 1) + 1.0f);
        const float* wl = wl_all + (size_t)i * NHID * NHID;
        const float* wg = wg_all + (size_t)i * NHID * NHID;
        const float* bl = bl_all + (size_t)i * NHID;
        const float* bg = bg_all + (size_t)i * NHID;
        for (int u = bid; u < LAYER_UNITS; u += G)
            d_layer(hbufs[i], h0, dinv, cnts, cols, wl, bl, wg, bg, beta,
                    obufs[i], fow, fob, out,
                    (i == 0) ? 1 : 0, (i == 3) ? 1 : 0, u * 8, tid, smem);
        if (i < 3) {
            __threadfence();
            grid.sync();
        }
    }
}

// ===========================================================================
// Fallback multi-kernel path (R9-equivalent, minus k_scale)
// ===========================================================================
__global__ __launch_bounds__(256) void k_pre(
    const float* __restrict__ x, const float* __restrict__ w,
    const float* __restrict__ b, const float* __restrict__ cvec,
    const float* __restrict__ adj,
    float* __restrict__ h, float* __restrict__ h0,
    float* __restrict__ dinv, int* __restrict__ cnts, int* __restrict__ cols)
{
    __shared__ float smem[SMEM_FLOATS];
    if (blockIdx.x < FCIN_UNITS)
        d_fcin(x, w, b, cvec, h, h0, blockIdx.x * 8, threadIdx.x, smem);
    else
        d_csr(adj, dinv, cnts, cols, (blockIdx.x - FCIN_UNITS) * 4, threadIdx.x);
}

__global__ __launch_bounds__(256) void k_layer(
    const float* __restrict__ hin, const float* __restrict__ h0,
    const float* __restrict__ dinv, const int* __restrict__ cnts,
    const int* __restrict__ cols,
    const float* __restrict__ wlin, const float* __restrict__ blin,
    const float* __restrict__ wgm, const float* __restrict__ bg,
    float beta, float* __restrict__ htout,
    const float* __restrict__ fow, const float* __restrict__ fob,
    float* __restrict__ out, int edge_dinv, int final_layer)
{
    __shared__ float smem[SMEM_FLOATS];
    d_layer(hin, h0, dinv, cnts, cols, wlin, blin, wgm, bg, beta, htout,
            fow, fob, out, edge_dinv, final_layer, blockIdx.x * 8,
            threadIdx.x, smem);
}

extern "C" void kernel_launch(void* const* d_in, const int* in_sizes, int n_in,
                              void* d_out, int out_size, void* d_ws, size_t ws_size,
                              hipStream_t stream) {
    const float* x        = (const float*)d_in[0];
    const float* adj      = (const float*)d_in[1];
    const float* fc_in_w  = (const float*)d_in[2];
    const float* fc_in_b  = (const float*)d_in[3];
    const float* cvec     = (const float*)d_in[4];
    const float* w_gcnii  = (const float*)d_in[5];
    const float* b_gcnii  = (const float*)d_in[6];
    const float* w_lin    = (const float*)d_in[7];
    const float* b_lin    = (const float*)d_in[8];
    const float* fc_out_w = (const float*)d_in[9];
    const float* fc_out_b = (const float*)d_in[10];
    float* out = (float*)d_out;

    char* ws = (char*)d_ws;
    size_t off = 0;
    auto alloc = [&](size_t bytes) -> void* {
        void* p = ws + off;
        off += (bytes + 255) & ~(size_t)255;
        return p;
    };
    float* dinv = (float*)alloc((size_t)NROWS * 4);
    int*   cnts = (int*)  alloc((size_t)NROWS * 4);
    int*   cols = (int*)  alloc((size_t)NROWS * CAP * 4);
    float* hA   = (float*)alloc((size_t)NROWS * NHID * 4);
    float* h0   = (float*)alloc((size_t)NROWS * NHID * 4);
    float* htA  = (float*)alloc((size_t)NROWS * NHID * 4);
    float* htB  = (float*)alloc((size_t)NROWS * NHID * 4);

    // ---- try cooperative mega-kernel, sized to actual occupancy ----
    bool coop_done = false;
    int occ = 0;
    hipError_t qe = hipOccupancyMaxActiveBlocksPerMultiprocessor(
        &occ, (const void*)k_mega, 256, 0);
    if (qe == hipSuccess && occ > 0) {
        int G = occ * 256;                 // 256 CUs on MI355X
        if (G > 1024) G = 1024;
        void* args[] = {
            (void*)&x, (void*)&adj, (void*)&fc_in_w, (void*)&fc_in_b,
            (void*)&cvec, (void*)&w_gcnii, (void*)&b_gcnii, (void*)&w_lin,
            (void*)&b_lin, (void*)&fc_out_w, (void*)&fc_out_b,
            (void*)&out, (void*)&dinv, (void*)&cnts, (void*)&cols,
            (void*)&hA, (void*)&h0, (void*)&htA, (void*)&htB,
        };
        hipError_t le = hipLaunchCooperativeKernel(
            (const void*)k_mega, dim3(G), dim3(256), args, 0, stream);
        coop_done = (le == hipSuccess);
    }

    if (!coop_done) {
        // ---- fallback: proven multi-kernel path ----
        k_pre<<<FCIN_UNITS + CSR_UNITS, 256, 0, stream>>>(
            x, fc_in_w, fc_in_b, cvec, adj, hA, h0, dinv, cnts, cols);
        const float* hbufs[4] = {hA, htA, htB, htA};
        float* obufs[4] = {htA, htB, htA, nullptr};
        for (int i = 0; i < 4; ++i) {
            float beta = logf(0.5f / (float)(i + 1) + 1.0f);
            k_layer<<<LAYER_UNITS, 256, 0, stream>>>(
                hbufs[i], h0, dinv, cnts, cols,
                w_lin + (size_t)i * NHID * NHID, b_lin + (size_t)i * NHID,
                w_gcnii + (size_t)i * NHID * NHID, b_gcnii + (size_t)i * NHID,
                beta, obufs[i], fc_out_w, fc_out_b, out,
                (i == 0) ? 1 : 0, (i == 3) ? 1 : 0);
        }
    }
}

// Round 11
// 208.450 us; speedup vs baseline: 3.6659x; 3.6659x over previous
//
#include <hip/hip_runtime.h>
#include <hip/hip_cooperative_groups.h>
#include <math.h>

namespace cg = cooperative_groups;

#define NROWS 8192
#define NFEATD 500
#define NHID 128
#define NCLS 40
#define CAP 64             // max nnz/row (mean ~16.4, binomial max ~41)
#define FCIN_UNITS (NROWS / 8)    // 1024 (8 rows each)
#define CSR_UNITS  (NROWS / 4)    // 2048 (4 rows each)
#define LAYER_UNITS (NROWS / 8)   // 1024 (8 rows each)
#define SMEM_FLOATS 4032          // max(8*504 fcin, 2*8*128 layer)

typedef float f32x4 __attribute__((ext_vector_type(4)));

// ===========================================================================
// Device bodies (shared by cooperative mega-kernel and multi-kernel fallback)
// ===========================================================================

// fcin unit: 8 rows. h = 0.9*relu(x@fc_in_w + b) + 0.1*c ; h0 = h  (R4-verbatim)
__device__ __forceinline__ void d_fcin(
    const float* __restrict__ x, const float* __restrict__ w,
    const float* __restrict__ b, const float* __restrict__ cvec,
    float* __restrict__ h, float* __restrict__ h0,
    int r0, int tid, float* smemf)
{
    float (*xs)[504] = (float(*)[504])smemf;
    __syncthreads();                       // protect LDS reuse across units
    for (int rr = 0; rr < 8; ++rr)
        for (int k = tid; k < NFEATD; k += 256)
            xs[rr][k] = x[(size_t)(r0 + rr) * NFEATD + k];
    __syncthreads();
    int col = tid & 127;
    int rg = tid >> 7;
    float bias = b[col];
    float acc[4] = {bias, bias, bias, bias};
    for (int k4 = 0; k4 < NFEATD / 4; ++k4) {
        int k = k4 * 4;
        f32x4 a0 = *(const f32x4*)&xs[rg * 4 + 0][k];
        f32x4 a1 = *(const f32x4*)&xs[rg * 4 + 1][k];
        f32x4 a2 = *(const f32x4*)&xs[rg * 4 + 2][k];
        f32x4 a3 = *(const f32x4*)&xs[rg * 4 + 3][k];
        float w0 = w[(k + 0) * NHID + col];
        float w1 = w[(k + 1) * NHID + col];
        float w2 = w[(k + 2) * NHID + col];
        float w3 = w[(k + 3) * NHID + col];
        acc[0] += a0.x * w0 + a0.y * w1 + a0.z * w2 + a0.w * w3;
        acc[1] += a1.x * w0 + a1.y * w1 + a1.z * w2 + a1.w * w3;
        acc[2] += a2.x * w0 + a2.y * w1 + a2.z * w2 + a2.w * w3;
        acc[3] += a3.x * w0 + a3.y * w1 + a3.z * w2 + a3.w * w3;
    }
    float cv = cvec[col];
#pragma unroll
    for (int rr = 0; rr < 4; ++rr) {
        float hv = 0.9f * fmaxf(acc[rr], 0.0f) + 0.1f * cv;
        size_t o = (size_t)(r0 + rg * 4 + rr) * NHID + col;
        h[o] = hv;
        h0[o] = hv;
    }
}

// csr unit: 4 rows (one per wave). Ordered CSR + dinv = rsqrt(deg+1). (R4-verbatim)
__device__ __forceinline__ void d_csr(
    const float* __restrict__ adj, float* __restrict__ dinv,
    int* __restrict__ cnts, int* __restrict__ cols, int rbase, int tid)
{
    int r = rbase + (tid >> 6);
    int lane = tid & 63;
    const f32x4* row4 = (const f32x4*)(adj + (size_t)r * NROWS);
    int* mycols = cols + (size_t)r * CAP;
    unsigned long long lt = (1ull << lane) - 1ull;
    int cnt = 0;
    for (int it = 0; it < NROWS / 256; ++it) {
        f32x4 v = __builtin_nontemporal_load(&row4[it * 64 + lane]);
        int base = it * 256 + 4 * lane;
        bool nz; unsigned long long m;
        nz = (v.x != 0.0f); m = __ballot(nz);
        if (nz) { int p = cnt + __popcll(m & lt); mycols[p < CAP ? p : CAP - 1] = base; }
        cnt += __popcll(m);
        nz = (v.y != 0.0f); m = __ballot(nz);
        if (nz) { int p = cnt + __popcll(m & lt); mycols[p < CAP ? p : CAP - 1] = base + 1; }
        cnt += __popcll(m);
        nz = (v.z != 0.0f); m = __ballot(nz);
        if (nz) { int p = cnt + __popcll(m & lt); mycols[p < CAP ? p : CAP - 1] = base + 2; }
        cnt += __popcll(m);
        nz = (v.w != 0.0f); m = __ballot(nz);
        if (nz) { int p = cnt + __popcll(m & lt); mycols[p < CAP ? p : CAP - 1] = base + 3; }
        cnt += __popcll(m);
    }
    if (lane == 0) {
        cnts[r] = cnt < CAP ? cnt : CAP;
        dinv[r] = rsqrtf((float)cnt + 1.0f);
    }
}

// layer unit: 8 rows. gather -> LDS, fused dual GEMM (4x1 tile), epilogue.
__device__ __forceinline__ void d_layer(
    const float* __restrict__ hin, const float* __restrict__ h0,
    const float* __restrict__ dinv, const int* __restrict__ cnts,
    const int* __restrict__ cols,
    const float* __restrict__ wlin, const float* __restrict__ blin,
    const float* __restrict__ wgm, const float* __restrict__ bg,
    float beta, float* __restrict__ htout,
    const float* __restrict__ fow, const float* __restrict__ fob,
    float* __restrict__ out, int edge_dinv, int final_layer,
    int r0, int tid, float* smemf)
{
    float (*ahs)[NHID] = (float(*)[NHID])smemf;
    float (*ss)[NHID]  = (float(*)[NHID])(smemf + 8 * NHID);
    int lane = tid & 63;
    int wid = tid >> 6;
    const float2* h2 = (const float2*)hin;
    const float2* h02 = (const float2*)h0;

    __syncthreads();                       // protect LDS reuse across units
    for (int rr = 2 * wid; rr < 2 * wid + 2; ++rr) {
        int r = r0 + rr;
        int n = cnts[r];
        const int* mc = cols + (size_t)r * CAP;
        float ax = 0.f, ay = 0.f;
        int e = 0;
        if (edge_dinv) {
            for (; e + 4 <= n; e += 4) {
                int j0 = mc[e], j1 = mc[e + 1], j2 = mc[e + 2], j3 = mc[e + 3];
                float d0 = dinv[j0], d1 = dinv[j1], d2 = dinv[j2], d3 = dinv[j3];
                float2 v0 = h2[(size_t)j0 * 64 + lane];
                float2 v1 = h2[(size_t)j1 * 64 + lane];
                float2 v2 = h2[(size_t)j2 * 64 + lane];
                float2 v3 = h2[(size_t)j3 * 64 + lane];
                ax += d0 * v0.x + d1 * v1.x + d2 * v2.x + d3 * v3.x;
                ay += d0 * v0.y + d1 * v1.y + d2 * v2.y + d3 * v3.y;
            }
            for (; e < n; ++e) {
                int j = mc[e];
                float dj = dinv[j];
                float2 v = h2[(size_t)j * 64 + lane];
                ax += dj * v.x;
                ay += dj * v.y;
            }
            float di = dinv[r];
            float2 vi = h2[(size_t)r * 64 + lane];
            ax = di * (ax + di * vi.x);
            ay = di * (ay + di * vi.y);
        } else {
            for (; e + 4 <= n; e += 4) {
                int j0 = mc[e], j1 = mc[e + 1], j2 = mc[e + 2], j3 = mc[e + 3];
                float2 v0 = h2[(size_t)j0 * 64 + lane];
                float2 v1 = h2[(size_t)j1 * 64 + lane];
                float2 v2 = h2[(size_t)j2 * 64 + lane];
                float2 v3 = h2[(size_t)j3 * 64 + lane];
                ax += v0.x + v1.x + v2.x + v3.x;
                ay += v0.y + v1.y + v2.y + v3.y;
            }
            for (; e < n; ++e) {
                int j = mc[e];
                float2 v = h2[(size_t)j * 64 + lane];
                ax += v.x;
                ay += v.y;
            }
            float di = dinv[r];
            float2 ti = h2[(size_t)r * 64 + lane];
            ax = di * (ax + ti.x);
            ay = di * (ay + ti.y);
        }
        float2 h0v = h02[(size_t)r * 64 + lane];
        ((float2*)&ahs[rr][0])[lane] = make_float2(ax, ay);
        ((float2*)&ss[rr][0])[lane] =
            make_float2(0.9f * ax + 0.1f * h0v.x, 0.9f * ay + 0.1f * h0v.y);
    }
    __syncthreads();

    // GEMM: thread = 4 rows x 1 col (proven-fastest tile)
    int col = tid & 127;
    int rg = tid >> 7;
    float accl[4] = {0, 0, 0, 0};
    float accg[4] = {0, 0, 0, 0};
    for (int k4 = 0; k4 < NHID / 4; ++k4) {
        int k = 4 * k4;
        f32x4 a0 = *(const f32x4*)&ahs[rg * 4 + 0][k];
        f32x4 a1 = *(const f32x4*)&ahs[rg * 4 + 1][k];
        f32x4 a2 = *(const f32x4*)&ahs[rg * 4 + 2][k];
        f32x4 a3 = *(const f32x4*)&ahs[rg * 4 + 3][k];
        f32x4 s0 = *(const f32x4*)&ss[rg * 4 + 0][k];
        f32x4 s1 = *(const f32x4*)&ss[rg * 4 + 1][k];
        f32x4 s2 = *(const f32x4*)&ss[rg * 4 + 2][k];
        f32x4 s3 = *(const f32x4*)&ss[rg * 4 + 3][k];
        float wl0 = wlin[(k + 0) * NHID + col];
        float wl1 = wlin[(k + 1) * NHID + col];
        float wl2 = wlin[(k + 2) * NHID + col];
        float wl3 = wlin[(k + 3) * NHID + col];
        float wg0 = wgm[(k + 0) * NHID + col];
        float wg1 = wgm[(k + 1) * NHID + col];
        float wg2 = wgm[(k + 2) * NHID + col];
        float wg3 = wgm[(k + 3) * NHID + col];
        accl[0] += a0.x * wl0 + a0.y * wl1 + a0.z * wl2 + a0.w * wl3;
        accl[1] += a1.x * wl0 + a1.y * wl1 + a1.z * wl2 + a1.w * wl3;
        accl[2] += a2.x * wl0 + a2.y * wl1 + a2.z * wl2 + a2.w * wl3;
        accl[3] += a3.x * wl0 + a3.y * wl1 + a3.z * wl2 + a3.w * wl3;
        accg[0] += s0.x * wg0 + s0.y * wg1 + s0.z * wg2 + s0.w * wg3;
        accg[1] += s1.x * wg0 + s1.y * wg1 + s1.z * wg2 + s1.w * wg3;
        accg[2] += s2.x * wg0 + s2.y * wg1 + s2.z * wg2 + s2.w * wg3;
        accg[3] += s3.x * wg0 + s3.y * wg1 + s3.z * wg2 + s3.w * wg3;
    }
    float blv = blin[col], bgv = bg[col];
    float omb = 1.0f - beta;
    float o[4];
#pragma unroll
    for (int rr = 0; rr < 4; ++rr) {
        float sv = ss[rg * 4 + rr][col];
        float g = fmaxf(omb * sv + beta * accg[rr] + bgv, 0.0f);
        o[rr] = accl[rr] + blv + g;
    }

    if (!final_layer) {
#pragma unroll
        for (int rr = 0; rr < 4; ++rr) {
            int row = r0 + rg * 4 + rr;
            htout[(size_t)row * NHID + col] = dinv[row] * o[rr];
        }
    } else {
        __syncthreads();
#pragma unroll
        for (int rr = 0; rr < 4; ++rr)
            ahs[rg * 4 + rr][col] = o[rr];
        __syncthreads();
        int rr2 = tid >> 6, c2 = tid & 63;
        if (c2 < NCLS) {
#pragma unroll
            for (int half = 0; half < 2; ++half) {
                int lr = half * 4 + rr2;
                float acc = fob[c2];
                for (int k = 0; k < NHID; ++k)
                    acc += ahs[lr][k] * fow[k * NCLS + c2];
                out[(size_t)(r0 + lr) * NCLS + c2] = acc;
            }
        }
    }
}

// ===========================================================================
// Cooperative mega-kernel. waves_per_eu(4,4) pins the register allocator at
// 128 VGPR/wave (4 waves/SIMD = 4 blocks/CU): R10's VGPR_Count=64 showed the
// compiler spilling the GEMM fragments to scratch to chase 8 waves/SIMD ->
// L2-latency-bound crawl (VALU 7.5%, HBM 2.7%). This removes that incentive.
// ===========================================================================
__global__ __attribute__((amdgpu_waves_per_eu(4, 4))) __launch_bounds__(256)
void k_mega(
    const float* x, const float* adj,
    const float* fiw, const float* fib, const float* cvec,
    const float* wg_all, const float* bg_all,
    const float* wl_all, const float* bl_all,
    const float* fow, const float* fob,
    float* out, float* dinv, int* cnts, int* cols,
    float* hA, float* h0, float* htA, float* htB)
{
    cg::grid_group grid = cg::this_grid();
    __shared__ float smem[SMEM_FLOATS];
    const int tid = threadIdx.x;
    const int bid = blockIdx.x;
    const int G = gridDim.x;

    // ---- Phase A: fcin + CSR (parity order so HBM and VALU halves overlap)
    if (bid & 1) {
        for (int u = FCIN_UNITS + bid; u < FCIN_UNITS + CSR_UNITS; u += G)
            d_csr(adj, dinv, cnts, cols, (u - FCIN_UNITS) * 4, tid);
        for (int u = bid; u < FCIN_UNITS; u += G)
            d_fcin(x, fiw, fib, cvec, hA, h0, u * 8, tid, smem);
    } else {
        for (int u = bid; u < FCIN_UNITS; u += G)
            d_fcin(x, fiw, fib, cvec, hA, h0, u * 8, tid, smem);
        for (int u = FCIN_UNITS + bid; u < FCIN_UNITS + CSR_UNITS; u += G)
            d_csr(adj, dinv, cnts, cols, (u - FCIN_UNITS) * 4, tid);
    }
    __threadfence();
    grid.sync();

    // ---- Layers ----
    const float* hbufs[4]  = {hA, htA, htB, htA};
    float* obufs[4]        = {htA, htB, htA, nullptr};
    for (int i = 0; i < 4; ++i) {
        float beta = logf(0.5f / (float)(i + 1) + 1.0f);
        const float* wl = wl_all + (size_t)i * NHID * NHID;
        const float* wg = wg_all + (size_t)i * NHID * NHID;
        const float* bl = bl_all + (size_t)i * NHID;
        const float* bg = bg_all + (size_t)i * NHID;
        for (int u = bid; u < LAYER_UNITS; u += G)
            d_layer(hbufs[i], h0, dinv, cnts, cols, wl, bl, wg, bg, beta,
                    obufs[i], fow, fob, out,
                    (i == 0) ? 1 : 0, (i == 3) ? 1 : 0, u * 8, tid, smem);
        if (i < 3) {
            __threadfence();
            grid.sync();
        }
    }
}

// ===========================================================================
// Fallback multi-kernel path (R9-equivalent, minus k_scale)
// ===========================================================================
__global__ __launch_bounds__(256) void k_pre(
    const float* __restrict__ x, const float* __restrict__ w,
    const float* __restrict__ b, const float* __restrict__ cvec,
    const float* __restrict__ adj,
    float* __restrict__ h, float* __restrict__ h0,
    float* __restrict__ dinv, int* __restrict__ cnts, int* __restrict__ cols)
{
    __shared__ float smem[SMEM_FLOATS];
    if (blockIdx.x < FCIN_UNITS)
        d_fcin(x, w, b, cvec, h, h0, blockIdx.x * 8, threadIdx.x, smem);
    else
        d_csr(adj, dinv, cnts, cols, (blockIdx.x - FCIN_UNITS) * 4, threadIdx.x);
}

__global__ __launch_bounds__(256) void k_layer(
    const float* __restrict__ hin, const float* __restrict__ h0,
    const float* __restrict__ dinv, const int* __restrict__ cnts,
    const int* __restrict__ cols,
    const float* __restrict__ wlin, const float* __restrict__ blin,
    const float* __restrict__ wgm, const float* __restrict__ bg,
    float beta, float* __restrict__ htout,
    const float* __restrict__ fow, const float* __restrict__ fob,
    float* __restrict__ out, int edge_dinv, int final_layer)
{
    __shared__ float smem[SMEM_FLOATS];
    d_layer(hin, h0, dinv, cnts, cols, wlin, blin, wgm, bg, beta, htout,
            fow, fob, out, edge_dinv, final_layer, blockIdx.x * 8,
            threadIdx.x, smem);
}

extern "C" void kernel_launch(void* const* d_in, const int* in_sizes, int n_in,
                              void* d_out, int out_size, void* d_ws, size_t ws_size,
                              hipStream_t stream) {
    const float* x        = (const float*)d_in[0];
    const float* adj      = (const float*)d_in[1];
    const float* fc_in_w  = (const float*)d_in[2];
    const float* fc_in_b  = (const float*)d_in[3];
    const float* cvec     = (const float*)d_in[4];
    const float* w_gcnii  = (const float*)d_in[5];
    const float* b_gcnii  = (const float*)d_in[6];
    const float* w_lin    = (const float*)d_in[7];
    const float* b_lin    = (const float*)d_in[8];
    const float* fc_out_w = (const float*)d_in[9];
    const float* fc_out_b = (const float*)d_in[10];
    float* out = (float*)d_out;

    char* ws = (char*)d_ws;
    size_t off = 0;
    auto alloc = [&](size_t bytes) -> void* {
        void* p = ws + off;
        off += (bytes + 255) & ~(size_t)255;
        return p;
    };
    float* dinv = (float*)alloc((size_t)NROWS * 4);
    int*   cnts = (int*)  alloc((size_t)NROWS * 4);
    int*   cols = (int*)  alloc((size_t)NROWS * CAP * 4);
    float* hA   = (float*)alloc((size_t)NROWS * NHID * 4);
    float* h0   = (float*)alloc((size_t)NROWS * NHID * 4);
    float* htA  = (float*)alloc((size_t)NROWS * NHID * 4);
    float* htB  = (float*)alloc((size_t)NROWS * NHID * 4);

    // ---- cooperative mega-kernel only if all 1024 blocks can be resident ----
    bool coop_done = false;
    int occ = 0;
    hipError_t qe = hipOccupancyMaxActiveBlocksPerMultiprocessor(
        &occ, (const void*)k_mega, 256, 0);
    if (qe == hipSuccess && occ * 256 >= 1024) {
        void* args[] = {
            (void*)&x, (void*)&adj, (void*)&fc_in_w, (void*)&fc_in_b,
            (void*)&cvec, (void*)&w_gcnii, (void*)&b_gcnii, (void*)&w_lin,
            (void*)&b_lin, (void*)&fc_out_w, (void*)&fc_out_b,
            (void*)&out, (void*)&dinv, (void*)&cnts, (void*)&cols,
            (void*)&hA, (void*)&h0, (void*)&htA, (void*)&htB,
        };
        hipError_t le = hipLaunchCooperativeKernel(
            (const void*)k_mega, dim3(1024), dim3(256), args, 0, stream);
        coop_done = (le == hipSuccess);
    }

    if (!coop_done) {
        // ---- fallback: proven multi-kernel path ----
        k_pre<<<FCIN_UNITS + CSR_UNITS, 256, 0, stream>>>(
            x, fc_in_w, fc_in_b, cvec, adj, hA, h0, dinv, cnts, cols);
        const float* hbufs[4] = {hA, htA, htB, htA};
        float* obufs[4] = {htA, htB, htA, nullptr};
        for (int i = 0; i < 4; ++i) {
            float beta = logf(0.5f / (float)(i + 1) + 1.0f);
            k_layer<<<LAYER_UNITS, 256, 0, stream>>>(
                hbufs[i], h0, dinv, cnts, cols,
                w_lin + (size_t)i * NHID * NHID, b_lin + (size_t)i * NHID,
                w_gcnii + (size_t)i * NHID * NHID, b_gcnii + (size_t)i * NHID,
                beta, obufs[i], fc_out_w, fc_out_b, out,
                (i == 0) ? 1 : 0, (i == 3) ? 1 : 0);
        }
    }
}

// Round 12
// 201.480 us; speedup vs baseline: 3.7928x; 1.0346x over previous
//
#include <hip/hip_runtime.h>
#include <math.h>

#define NROWS 8192
#define NFEATD 500
#define NHID 128
#define NCLS 40
#define CAP 64            // max nnz/row (mean ~16.4, binomial max ~41)
#define FCIN_BLOCKS (NROWS / 8)   // 1024
#define CSR_BLOCKS  (NROWS / 4)   // 2048
#define ROWS_PB 8                 // rows per k_layer block (grid = 1024)

typedef float f32x4 __attribute__((ext_vector_type(4)));

// ---------------------------------------------------------------------------
// Kernel 1 (heterogeneous): blocks [0,1024) do fcin, blocks [1024,3072) do
// CSR build. (R4/R9-verbatim, proven 211/208 us baseline component.)
// ---------------------------------------------------------------------------
__global__ __launch_bounds__(256) void k_pre(
    const float* __restrict__ x, const float* __restrict__ w,
    const float* __restrict__ b, const float* __restrict__ c,
    const float* __restrict__ adj,
    float* __restrict__ h, float* __restrict__ h0,
    float* __restrict__ dinv, int* __restrict__ cnts, int* __restrict__ cols)
{
    __shared__ float xs[8][504];
    int tid = threadIdx.x;
    if (blockIdx.x < FCIN_BLOCKS) {
        int col = tid & 127;
        int rg = tid >> 7;
        int r0 = blockIdx.x * 8;
        for (int rr = 0; rr < 8; ++rr)
            for (int k = tid; k < NFEATD; k += 256)
                xs[rr][k] = x[(size_t)(r0 + rr) * NFEATD + k];
        __syncthreads();
        float bias = b[col];
        float acc[4] = {bias, bias, bias, bias};
        for (int k4 = 0; k4 < NFEATD / 4; ++k4) {
            int k = k4 * 4;
            f32x4 a0 = *(const f32x4*)&xs[rg * 4 + 0][k];
            f32x4 a1 = *(const f32x4*)&xs[rg * 4 + 1][k];
            f32x4 a2 = *(const f32x4*)&xs[rg * 4 + 2][k];
            f32x4 a3 = *(const f32x4*)&xs[rg * 4 + 3][k];
            float w0 = w[(k + 0) * NHID + col];
            float w1 = w[(k + 1) * NHID + col];
            float w2 = w[(k + 2) * NHID + col];
            float w3 = w[(k + 3) * NHID + col];
            acc[0] += a0.x * w0 + a0.y * w1 + a0.z * w2 + a0.w * w3;
            acc[1] += a1.x * w0 + a1.y * w1 + a1.z * w2 + a1.w * w3;
            acc[2] += a2.x * w0 + a2.y * w1 + a2.z * w2 + a2.w * w3;
            acc[3] += a3.x * w0 + a3.y * w1 + a3.z * w2 + a3.w * w3;
        }
        float cv = c[col];
#pragma unroll
        for (int rr = 0; rr < 4; ++rr) {
            float hv = 0.9f * fmaxf(acc[rr], 0.0f) + 0.1f * cv;
            size_t o = (size_t)(r0 + rg * 4 + rr) * NHID + col;
            h[o] = hv;
            h0[o] = hv;
        }
    } else {
        int bid = blockIdx.x - FCIN_BLOCKS;
        int r = bid * 4 + (tid >> 6);
        int lane = tid & 63;
        const f32x4* row4 = (const f32x4*)(adj + (size_t)r * NROWS);
        int* mycols = cols + (size_t)r * CAP;
        unsigned long long lt = (1ull << lane) - 1ull;
        int cnt = 0;
        for (int it = 0; it < NROWS / 256; ++it) {
            f32x4 v = __builtin_nontemporal_load(&row4[it * 64 + lane]);
            int base = it * 256 + 4 * lane;
            bool nz; unsigned long long m;
            nz = (v.x != 0.0f); m = __ballot(nz);
            if (nz) { int p = cnt + __popcll(m & lt); mycols[p < CAP ? p : CAP - 1] = base; }
            cnt += __popcll(m);
            nz = (v.y != 0.0f); m = __ballot(nz);
            if (nz) { int p = cnt + __popcll(m & lt); mycols[p < CAP ? p : CAP - 1] = base + 1; }
            cnt += __popcll(m);
            nz = (v.z != 0.0f); m = __ballot(nz);
            if (nz) { int p = cnt + __popcll(m & lt); mycols[p < CAP ? p : CAP - 1] = base + 2; }
            cnt += __popcll(m);
            nz = (v.w != 0.0f); m = __ballot(nz);
            if (nz) { int p = cnt + __popcll(m & lt); mycols[p < CAP ? p : CAP - 1] = base + 3; }
            cnt += __popcll(m);
        }
        if (lane == 0) {
            cnts[r] = cnt < CAP ? cnt : CAP;
            dinv[r] = rsqrtf((float)cnt + 1.0f);
        }
    }
}

// ---------------------------------------------------------------------------
// Kernel 1b: ht = dinv (row-wise) * h.  Tiny streaming kernel (R9-verbatim).
// ---------------------------------------------------------------------------
__global__ __launch_bounds__(256) void k_scale(
    const float* __restrict__ h, const float* __restrict__ dinv,
    float* __restrict__ ht)
{
    int gid = blockIdx.x * 256 + threadIdx.x;   // float2 index
    float2 v = ((const float2*)h)[gid];
    float d = dinv[gid >> 6];
    ((float2*)ht)[gid] = make_float2(v.x * d, v.y * d);
}

// ---------------------------------------------------------------------------
// Kernel 2 (per layer): gather (R9-verbatim, ht-based) then SPLIT dual GEMM:
//   threads tid>>7==0: accl = ahs @ wlin  (8 rows x 1 col each)
//   threads tid>>7==1: accg = ss  @ wg    (8 rows x 1 col each)
// Each weight matrix is read exactly ONCE per block (was twice in R4/R9):
// halves weight VMEM issue and L2 weight traffic. DS count/FMA unchanged.
// gcnii half deposits g in LDS (reusing ahs); lin half combines + stores.
// ---------------------------------------------------------------------------
__global__ __launch_bounds__(256) void k_layer(
    const float* __restrict__ ht, const float* __restrict__ h0,
    const float* __restrict__ dinv, const int* __restrict__ cnts,
    const int* __restrict__ cols,
    const float* __restrict__ wlin, const float* __restrict__ blin,
    const float* __restrict__ wg, const float* __restrict__ bg,
    float beta, float* __restrict__ htout,
    const float* __restrict__ fow, const float* __restrict__ fob,
    float* __restrict__ out, int final_layer)
{
    __shared__ float ahs[ROWS_PB][NHID];
    __shared__ float ss[ROWS_PB][NHID];
    int tid = threadIdx.x;
    int lane = tid & 63;
    int wid = tid >> 6;
    int r0 = blockIdx.x * ROWS_PB;
    const float2* ht2 = (const float2*)ht;
    const float2* h02 = (const float2*)h0;

    // ---- gather phase: wave wid handles rows 2*wid, 2*wid+1 (R9-verbatim) --
    for (int rr = 2 * wid; rr < 2 * wid + 2; ++rr) {
        int r = r0 + rr;
        int n = cnts[r];
        const int* mc = cols + (size_t)r * CAP;
        float ax = 0.f, ay = 0.f;
        int e = 0;
        for (; e + 4 <= n; e += 4) {
            int j0 = mc[e], j1 = mc[e + 1], j2 = mc[e + 2], j3 = mc[e + 3];
            float2 v0 = ht2[(size_t)j0 * 64 + lane];
            float2 v1 = ht2[(size_t)j1 * 64 + lane];
            float2 v2 = ht2[(size_t)j2 * 64 + lane];
            float2 v3 = ht2[(size_t)j3 * 64 + lane];
            ax += v0.x + v1.x + v2.x + v3.x;
            ay += v0.y + v1.y + v2.y + v3.y;
        }
        for (; e < n; ++e) {
            int j = mc[e];
            float2 v = ht2[(size_t)j * 64 + lane];
            ax += v.x;
            ay += v.y;
        }
        float di = dinv[r];
        float2 ti = ht2[(size_t)r * 64 + lane];   // ti = dinv[r]*h[r]
        float gx = di * (ax + ti.x);
        float gy = di * (ay + ti.y);
        float2 h0v = h02[(size_t)r * 64 + lane];
        ((float2*)&ahs[rr][0])[lane] = make_float2(gx, gy);
        ((float2*)&ss[rr][0])[lane] =
            make_float2(0.9f * gx + 0.1f * h0v.x, 0.9f * gy + 0.1f * h0v.y);
    }
    __syncthreads();

    // ---- split GEMM: branch 0 -> lin over ahs/wlin, branch 1 -> gcnii ----
    int col = tid & 127;
    int br = tid >> 7;
    const float* wmat = br ? wg : wlin;
    const float (*amat)[NHID] = br ? ss : ahs;
    float acc[8] = {0, 0, 0, 0, 0, 0, 0, 0};
    for (int k4 = 0; k4 < NHID / 4; ++k4) {
        int k = 4 * k4;
        f32x4 a0 = *(const f32x4*)&amat[0][k];
        f32x4 a1 = *(const f32x4*)&amat[1][k];
        f32x4 a2 = *(const f32x4*)&amat[2][k];
        f32x4 a3 = *(const f32x4*)&amat[3][k];
        f32x4 a4 = *(const f32x4*)&amat[4][k];
        f32x4 a5 = *(const f32x4*)&amat[5][k];
        f32x4 a6 = *(const f32x4*)&amat[6][k];
        f32x4 a7 = *(const f32x4*)&amat[7][k];
        float w0 = wmat[(k + 0) * NHID + col];
        float w1 = wmat[(k + 1) * NHID + col];
        float w2 = wmat[(k + 2) * NHID + col];
        float w3 = wmat[(k + 3) * NHID + col];
        acc[0] += a0.x * w0 + a0.y * w1 + a0.z * w2 + a0.w * w3;
        acc[1] += a1.x * w0 + a1.y * w1 + a1.z * w2 + a1.w * w3;
        acc[2] += a2.x * w0 + a2.y * w1 + a2.z * w2 + a2.w * w3;
        acc[3] += a3.x * w0 + a3.y * w1 + a3.z * w2 + a3.w * w3;
        acc[4] += a4.x * w0 + a4.y * w1 + a4.z * w2 + a4.w * w3;
        acc[5] += a5.x * w0 + a5.y * w1 + a5.z * w2 + a5.w * w3;
        acc[6] += a6.x * w0 + a6.y * w1 + a6.z * w2 + a6.w * w3;
        acc[7] += a7.x * w0 + a7.y * w1 + a7.z * w2 + a7.w * w3;
    }

    if (br == 1) {
        // gcnii epilogue: g = relu((1-beta)*s + beta*accg + bg) -> LDS (ahs)
        float bgv = bg[col];
        float omb = 1.0f - beta;
        float g[8];
#pragma unroll
        for (int rr = 0; rr < 8; ++rr)
            g[rr] = fmaxf(omb * ss[rr][col] + beta * acc[rr] + bgv, 0.0f);
        __syncthreads();            // ahs reads (branch 0) complete
#pragma unroll
        for (int rr = 0; rr < 8; ++rr)
            ahs[rr][col] = g[rr];
    } else {
        __syncthreads();            // matches branch-1 sync
    }
    __syncthreads();                // g visible to branch 0

    if (!final_layer) {
        if (br == 0) {
            float blv = blin[col];
#pragma unroll
            for (int rr = 0; rr < 8; ++rr) {
                int row = r0 + rr;
                float o = acc[rr] + blv + ahs[rr][col];
                htout[(size_t)row * NHID + col] = dinv[row] * o;
            }
        }
    } else {
        // stage h = lin + g into ss, then fcout: out = h @ fow + fob
        if (br == 0) {
            float blv = blin[col];
#pragma unroll
            for (int rr = 0; rr < 8; ++rr)
                ss[rr][col] = acc[rr] + blv + ahs[rr][col];
        }
        __syncthreads();
        int rr2 = tid >> 6, c2 = tid & 63;
        if (c2 < NCLS) {
#pragma unroll
            for (int half = 0; half < 2; ++half) {
                int lr = half * 4 + rr2;
                float a = fob[c2];
                for (int k = 0; k < NHID; ++k)
                    a += ss[lr][k] * fow[k * NCLS + c2];
                out[(size_t)(r0 + lr) * NCLS + c2] = a;
            }
        }
    }
}

extern "C" void kernel_launch(void* const* d_in, const int* in_sizes, int n_in,
                              void* d_out, int out_size, void* d_ws, size_t ws_size,
                              hipStream_t stream) {
    const float* x        = (const float*)d_in[0];
    const float* adj      = (const float*)d_in[1];
    const float* fc_in_w  = (const float*)d_in[2];
    const float* fc_in_b  = (const float*)d_in[3];
    const float* c        = (const float*)d_in[4];
    const float* w_gcnii  = (const float*)d_in[5];
    const float* b_gcnii  = (const float*)d_in[6];
    const float* w_lin    = (const float*)d_in[7];
    const float* b_lin    = (const float*)d_in[8];
    const float* fc_out_w = (const float*)d_in[9];
    const float* fc_out_b = (const float*)d_in[10];
    float* out = (float*)d_out;

    char* ws = (char*)d_ws;
    size_t off = 0;
    auto alloc = [&](size_t bytes) -> void* {
        void* p = ws + off;
        off += (bytes + 255) & ~(size_t)255;
        return p;
    };
    float* dinv = (float*)alloc((size_t)NROWS * 4);
    int*   cnts = (int*)  alloc((size_t)NROWS * 4);
    int*   cols = (int*)  alloc((size_t)NROWS * CAP * 4);
    float* hA   = (float*)alloc((size_t)NROWS * NHID * 4);
    float* h0   = (float*)alloc((size_t)NROWS * NHID * 4);
    float* htA  = (float*)alloc((size_t)NROWS * NHID * 4);
    float* htB  = (float*)alloc((size_t)NROWS * NHID * 4);

    k_pre<<<FCIN_BLOCKS + CSR_BLOCKS, 256, 0, stream>>>(
        x, fc_in_w, fc_in_b, c, adj, hA, h0, dinv, cnts, cols);
    k_scale<<<NROWS * 64 / 256, 256, 0, stream>>>(hA, dinv, htA);

    float* htb[2] = {htA, htB};
    for (int i = 0; i < 4; ++i) {
        float beta = logf(0.5f / (float)(i + 1) + 1.0f);
        k_layer<<<NROWS / ROWS_PB, 256, 0, stream>>>(
            htb[i & 1], h0, dinv, cnts, cols,
            w_lin + (size_t)i * NHID * NHID, b_lin + (size_t)i * NHID,
            w_gcnii + (size_t)i * NHID * NHID, b_gcnii + (size_t)i * NHID,
            beta, htb[(i + 1) & 1],
            fc_out_w, fc_out_b, out, (i == 3) ? 1 : 0);
    }
}

// Round 13
// 186.419 us; speedup vs baseline: 4.0992x; 1.0808x over previous
//
#include <hip/hip_runtime.h>
#include <math.h>

#define NROWS 8192
#define NFEATD 500
#define NHID 128
#define NCLS 40
#define CAP 64            // max nnz/row (mean ~16.4, binomial max ~41)
#define FCIN_BLOCKS (NROWS / 8)   // 1024
#define CSR_BLOCKS  (NROWS / 4)   // 2048
#define ROWS_PB 8                 // rows per k_layer block (grid = 1024)

typedef float f32x4 __attribute__((ext_vector_type(4)));
typedef float f32x2 __attribute__((ext_vector_type(2)));

// ---------------------------------------------------------------------------
// Kernel 1 (heterogeneous): blocks [0,1024) do fcin, blocks [1024,3072) do
// CSR build. (R4/R9/R12-verbatim.)
// ---------------------------------------------------------------------------
__global__ __launch_bounds__(256) void k_pre(
    const float* __restrict__ x, const float* __restrict__ w,
    const float* __restrict__ b, const float* __restrict__ c,
    const float* __restrict__ adj,
    float* __restrict__ h, float* __restrict__ h0,
    float* __restrict__ dinv, int* __restrict__ cnts, int* __restrict__ cols)
{
    __shared__ float xs[8][504];
    int tid = threadIdx.x;
    if (blockIdx.x < FCIN_BLOCKS) {
        int col = tid & 127;
        int rg = tid >> 7;
        int r0 = blockIdx.x * 8;
        for (int rr = 0; rr < 8; ++rr)
            for (int k = tid; k < NFEATD; k += 256)
                xs[rr][k] = x[(size_t)(r0 + rr) * NFEATD + k];
        __syncthreads();
        float bias = b[col];
        float acc[4] = {bias, bias, bias, bias};
        for (int k4 = 0; k4 < NFEATD / 4; ++k4) {
            int k = k4 * 4;
            f32x4 a0 = *(const f32x4*)&xs[rg * 4 + 0][k];
            f32x4 a1 = *(const f32x4*)&xs[rg * 4 + 1][k];
            f32x4 a2 = *(const f32x4*)&xs[rg * 4 + 2][k];
            f32x4 a3 = *(const f32x4*)&xs[rg * 4 + 3][k];
            float w0 = w[(k + 0) * NHID + col];
            float w1 = w[(k + 1) * NHID + col];
            float w2 = w[(k + 2) * NHID + col];
            float w3 = w[(k + 3) * NHID + col];
            acc[0] += a0.x * w0 + a0.y * w1 + a0.z * w2 + a0.w * w3;
            acc[1] += a1.x * w0 + a1.y * w1 + a1.z * w2 + a1.w * w3;
            acc[2] += a2.x * w0 + a2.y * w1 + a2.z * w2 + a2.w * w3;
            acc[3] += a3.x * w0 + a3.y * w1 + a3.z * w2 + a3.w * w3;
        }
        float cv = c[col];
#pragma unroll
        for (int rr = 0; rr < 4; ++rr) {
            float hv = 0.9f * fmaxf(acc[rr], 0.0f) + 0.1f * cv;
            size_t o = (size_t)(r0 + rg * 4 + rr) * NHID + col;
            h[o] = hv;
            h0[o] = hv;
        }
    } else {
        int bid = blockIdx.x - FCIN_BLOCKS;
        int r = bid * 4 + (tid >> 6);
        int lane = tid & 63;
        const f32x4* row4 = (const f32x4*)(adj + (size_t)r * NROWS);
        int* mycols = cols + (size_t)r * CAP;
        unsigned long long lt = (1ull << lane) - 1ull;
        int cnt = 0;
        for (int it = 0; it < NROWS / 256; ++it) {
            f32x4 v = __builtin_nontemporal_load(&row4[it * 64 + lane]);
            int base = it * 256 + 4 * lane;
            bool nz; unsigned long long m;
            nz = (v.x != 0.0f); m = __ballot(nz);
            if (nz) { int p = cnt + __popcll(m & lt); mycols[p < CAP ? p : CAP - 1] = base; }
            cnt += __popcll(m);
            nz = (v.y != 0.0f); m = __ballot(nz);
            if (nz) { int p = cnt + __popcll(m & lt); mycols[p < CAP ? p : CAP - 1] = base + 1; }
            cnt += __popcll(m);
            nz = (v.z != 0.0f); m = __ballot(nz);
            if (nz) { int p = cnt + __popcll(m & lt); mycols[p < CAP ? p : CAP - 1] = base + 2; }
            cnt += __popcll(m);
            nz = (v.w != 0.0f); m = __ballot(nz);
            if (nz) { int p = cnt + __popcll(m & lt); mycols[p < CAP ? p : CAP - 1] = base + 3; }
            cnt += __popcll(m);
        }
        if (lane == 0) {
            cnts[r] = cnt < CAP ? cnt : CAP;
            dinv[r] = rsqrtf((float)cnt + 1.0f);
        }
    }
}

// ---------------------------------------------------------------------------
// Kernel 1b: ht = dinv (row-wise) * h.  (R9-verbatim)
// ---------------------------------------------------------------------------
__global__ __launch_bounds__(256) void k_scale(
    const float* __restrict__ h, const float* __restrict__ dinv,
    float* __restrict__ ht)
{
    int gid = blockIdx.x * 256 + threadIdx.x;   // float2 index
    float2 v = ((const float2*)h)[gid];
    float d = dinv[gid >> 6];
    ((float2*)ht)[gid] = make_float2(v.x * d, v.y * d);
}

// ---------------------------------------------------------------------------
// Kernel 2 (per layer): gather (R9-verbatim) then split-matrix + SPLIT-K GEMM:
//   br = tid>>7 selects matrix (0: ahs@wlin, 1: ss@wg)
//   kh = (tid>>6)&1 selects k-half (0..63 / 64..127)  -> 16 k4 iters per wave
//   cp = tid&63 -> cols {2cp, 2cp+1}, f32x2 weights (each weight read ONCE)
// GEMM DS instrs per block halve vs R12 (512 vs 1024): the modeled ~10us/layer
// DS-issue term. Partials combined via an 8KB LDS exchange.
// ---------------------------------------------------------------------------
__global__ __launch_bounds__(256) void k_layer(
    const float* __restrict__ ht, const float* __restrict__ h0,
    const float* __restrict__ dinv, const int* __restrict__ cnts,
    const int* __restrict__ cols,
    const float* __restrict__ wlin, const float* __restrict__ blin,
    const float* __restrict__ wg, const float* __restrict__ bg,
    float beta, float* __restrict__ htout,
    const float* __restrict__ fow, const float* __restrict__ fob,
    float* __restrict__ out, int final_layer)
{
    __shared__ float ahs[ROWS_PB][NHID];
    __shared__ float ss[ROWS_PB][NHID];
    __shared__ float red[2][ROWS_PB][NHID];   // kh=1 partials; red[0] reused for g
    int tid = threadIdx.x;
    int lane = tid & 63;
    int wid = tid >> 6;
    int r0 = blockIdx.x * ROWS_PB;
    const float2* ht2 = (const float2*)ht;
    const float2* h02 = (const float2*)h0;

    // ---- gather phase: wave wid handles rows 2*wid, 2*wid+1 (R9-verbatim) --
    for (int rr = 2 * wid; rr < 2 * wid + 2; ++rr) {
        int r = r0 + rr;
        int n = cnts[r];
        const int* mc = cols + (size_t)r * CAP;
        float ax = 0.f, ay = 0.f;
        int e = 0;
        for (; e + 4 <= n; e += 4) {
            int j0 = mc[e], j1 = mc[e + 1], j2 = mc[e + 2], j3 = mc[e + 3];
            float2 v0 = ht2[(size_t)j0 * 64 + lane];
            float2 v1 = ht2[(size_t)j1 * 64 + lane];
            float2 v2 = ht2[(size_t)j2 * 64 + lane];
            float2 v3 = ht2[(size_t)j3 * 64 + lane];
            ax += v0.x + v1.x + v2.x + v3.x;
            ay += v0.y + v1.y + v2.y + v3.y;
        }
        for (; e < n; ++e) {
            int j = mc[e];
            float2 v = ht2[(size_t)j * 64 + lane];
            ax += v.x;
            ay += v.y;
        }
        float di = dinv[r];
        float2 ti = ht2[(size_t)r * 64 + lane];   // ti = dinv[r]*h[r]
        float gx = di * (ax + ti.x);
        float gy = di * (ay + ti.y);
        float2 h0v = h02[(size_t)r * 64 + lane];
        ((float2*)&ahs[rr][0])[lane] = make_float2(gx, gy);
        ((float2*)&ss[rr][0])[lane] =
            make_float2(0.9f * gx + 0.1f * h0v.x, 0.9f * gy + 0.1f * h0v.y);
    }
    __syncthreads();

    // ---- split-k split-matrix GEMM ----
    int br = tid >> 7;          // matrix select (wave-uniform)
    int kh = (tid >> 6) & 1;    // k-half (wave-uniform)
    int cp = tid & 63;          // col pair: cols 2cp, 2cp+1
    const float* wmat = br ? wg : wlin;
    const float (*amat)[NHID] = br ? ss : ahs;
    f32x2 acc[8] = {{0,0},{0,0},{0,0},{0,0},{0,0},{0,0},{0,0},{0,0}};
    int kbase = kh * 64;
    for (int k4 = 0; k4 < 16; ++k4) {
        int k = kbase + 4 * k4;
        f32x4 a0 = *(const f32x4*)&amat[0][k];
        f32x4 a1 = *(const f32x4*)&amat[1][k];
        f32x4 a2 = *(const f32x4*)&amat[2][k];
        f32x4 a3 = *(const f32x4*)&amat[3][k];
        f32x4 a4 = *(const f32x4*)&amat[4][k];
        f32x4 a5 = *(const f32x4*)&amat[5][k];
        f32x4 a6 = *(const f32x4*)&amat[6][k];
        f32x4 a7 = *(const f32x4*)&amat[7][k];
        f32x2 w0 = ((const f32x2*)&wmat[(size_t)(k + 0) * NHID])[cp];
        f32x2 w1 = ((const f32x2*)&wmat[(size_t)(k + 1) * NHID])[cp];
        f32x2 w2 = ((const f32x2*)&wmat[(size_t)(k + 2) * NHID])[cp];
        f32x2 w3 = ((const f32x2*)&wmat[(size_t)(k + 3) * NHID])[cp];
        acc[0] += a0.x * w0 + a0.y * w1 + a0.z * w2 + a0.w * w3;
        acc[1] += a1.x * w0 + a1.y * w1 + a1.z * w2 + a1.w * w3;
        acc[2] += a2.x * w0 + a2.y * w1 + a2.z * w2 + a2.w * w3;
        acc[3] += a3.x * w0 + a3.y * w1 + a3.z * w2 + a3.w * w3;
        acc[4] += a4.x * w0 + a4.y * w1 + a4.z * w2 + a4.w * w3;
        acc[5] += a5.x * w0 + a5.y * w1 + a5.z * w2 + a5.w * w3;
        acc[6] += a6.x * w0 + a6.y * w1 + a6.z * w2 + a6.w * w3;
        acc[7] += a7.x * w0 + a7.y * w1 + a7.z * w2 + a7.w * w3;
    }

    // kh=1 partials -> LDS
    if (kh == 1) {
#pragma unroll
        for (int rr = 0; rr < 8; ++rr)
            ((f32x2*)&red[br][rr][0])[cp] = acc[rr];
    }
    __syncthreads();
    // kh=0 combines
    if (kh == 0) {
#pragma unroll
        for (int rr = 0; rr < 8; ++rr)
            acc[rr] += ((const f32x2*)&red[br][rr][0])[cp];
    }
    // gcnii epilogue on br1/kh0 (reads ss before red[0] is overwritten)
    f32x2 gv[8];
    if (br == 1 && kh == 0) {
        f32x2 bgv = ((const f32x2*)bg)[cp];
        float omb = 1.0f - beta;
#pragma unroll
        for (int rr = 0; rr < 8; ++rr) {
            f32x2 sv = ((const f32x2*)&ss[rr][0])[cp];
            f32x2 t = omb * sv + beta * acc[rr] + bgv;
            gv[rr].x = fmaxf(t.x, 0.f);
            gv[rr].y = fmaxf(t.y, 0.f);
        }
    }
    __syncthreads();            // red reads complete
    if (br == 1 && kh == 0) {
#pragma unroll
        for (int rr = 0; rr < 8; ++rr)
            ((f32x2*)&red[0][rr][0])[cp] = gv[rr];
    }
    __syncthreads();            // g visible

    if (!final_layer) {
        if (br == 0 && kh == 0) {
            f32x2 blv = ((const f32x2*)blin)[cp];
#pragma unroll
            for (int rr = 0; rr < 8; ++rr) {
                int row = r0 + rr;
                f32x2 g = ((const f32x2*)&red[0][rr][0])[cp];
                f32x2 o = acc[rr] + blv + g;
                ((f32x2*)htout)[(size_t)row * 64 + cp] = dinv[row] * o;
            }
        }
    } else {
        // stage h = lin + g into ss, then fcout: out = h @ fow + fob
        if (br == 0 && kh == 0) {
            f32x2 blv = ((const f32x2*)blin)[cp];
#pragma unroll
            for (int rr = 0; rr < 8; ++rr) {
                f32x2 g = ((const f32x2*)&red[0][rr][0])[cp];
                ((f32x2*)&ss[rr][0])[cp] = acc[rr] + blv + g;
            }
        }
        __syncthreads();
        int rr2 = tid >> 6, c2 = tid & 63;
        if (c2 < NCLS) {
#pragma unroll
            for (int half = 0; half < 2; ++half) {
                int lr = half * 4 + rr2;
                float a = fob[c2];
                for (int k = 0; k < NHID; ++k)
                    a += ss[lr][k] * fow[k * NCLS + c2];
                out[(size_t)(r0 + lr) * NCLS + c2] = a;
            }
        }
    }
}

extern "C" void kernel_launch(void* const* d_in, const int* in_sizes, int n_in,
                              void* d_out, int out_size, void* d_ws, size_t ws_size,
                              hipStream_t stream) {
    const float* x        = (const float*)d_in[0];
    const float* adj      = (const float*)d_in[1];
    const float* fc_in_w  = (const float*)d_in[2];
    const float* fc_in_b  = (const float*)d_in[3];
    const float* c        = (const float*)d_in[4];
    const float* w_gcnii  = (const float*)d_in[5];
    const float* b_gcnii  = (const float*)d_in[6];
    const float* w_lin    = (const float*)d_in[7];
    const float* b_lin    = (const float*)d_in[8];
    const float* fc_out_w = (const float*)d_in[9];
    const float* fc_out_b = (const float*)d_in[10];
    float* out = (float*)d_out;

    char* ws = (char*)d_ws;
    size_t off = 0;
    auto alloc = [&](size_t bytes) -> void* {
        void* p = ws + off;
        off += (bytes + 255) & ~(size_t)255;
        return p;
    };
    float* dinv = (float*)alloc((size_t)NROWS * 4);
    int*   cnts = (int*)  alloc((size_t)NROWS * 4);
    int*   cols = (int*)  alloc((size_t)NROWS * CAP * 4);
    float* hA   = (float*)alloc((size_t)NROWS * NHID * 4);
    float* h0   = (float*)alloc((size_t)NROWS * NHID * 4);
    float* htA  = (float*)alloc((size_t)NROWS * NHID * 4);
    float* htB  = (float*)alloc((size_t)NROWS * NHID * 4);

    k_pre<<<FCIN_BLOCKS + CSR_BLOCKS, 256, 0, stream>>>(
        x, fc_in_w, fc_in_b, c, adj, hA, h0, dinv, cnts, cols);
    k_scale<<<NROWS * 64 / 256, 256, 0, stream>>>(hA, dinv, htA);

    float* htb[2] = {htA, htB};
    for (int i = 0; i < 4; ++i) {
        float beta = logf(0.5f / (float)(i + 1) + 1.0f);
        k_layer<<<NROWS / ROWS_PB, 256, 0, stream>>>(
            htb[i & 1], h0, dinv, cnts, cols,
            w_lin + (size_t)i * NHID * NHID, b_lin + (size_t)i * NHID,
            w_gcnii + (size_t)i * NHID * NHID, b_gcnii + (size_t)i * NHID,
            beta, htb[(i + 1) & 1],
            fc_out_w, fc_out_b, out, (i == 3) ? 1 : 0);
    }
}